// Round 6
// baseline (198.218 us; speedup 1.0000x reference)
//
#include <hip/hip_runtime.h>
#include <cstddef>

// DynamicRouting: B=32, C1=4096, C2=32, D2=16, 3 routing iterations.
// digit_caps_stopped == digit_caps (bit-identical) -> read d_in[0] only.
//
// iter0: w = 1/32 uniform            -> v0 = squash(colsum(x)/32 + bias)
// iter1: w1 = softmax_c2(x.v0)       -> v1 = squash(sum_c1 w1*x + bias)
// iter2: w2 = softmax_c2(x.(v0+v1))  -> out = squash(sum_c1 w2*x + bias)
//
// R6 = R5 + MEASUREMENT PROBE: pass1 is launched TWICE (second launch reads
// the same inputs and rewrites the identical P1 -- deterministic, correct).
// dur(R6) - dur(R5) isolates T(passN), invisible in rocprof top-5 (clogged
// by harness fills). This decides whether R7 rewrites pass0 (mixed-stream /
// nt-load / lane-stride pattern) or passN (softmax latency chain).

namespace {
typedef float  v2f __attribute__((ext_vector_type(2)));
typedef float  v4f __attribute__((ext_vector_type(4)));
typedef unsigned int v4u __attribute__((ext_vector_type(4)));

constexpr int B_  = 32;
constexpr int C1_ = 4096;
constexpr int C2_ = 32;
constexpr int D2_ = 16;
constexpr int ROW_ = C2_ * D2_;   // 512 elems per (b,c1)
constexpr int BPB  = 16;          // partial blocks per batch element
constexpr int C1B  = C1_ / BPB;   // 256 rows per block
constexpr int TPB  = 1024;        // threads per block (16 waves)

__device__ inline void pk_fma(v2f& c, v2f a, v2f b) {
  asm("v_pk_fma_f32 %0, %1, %2, %0" : "+v"(c) : "v"(a), "v"(b));
}
__device__ inline void pk_add(v2f& c, v2f a) {
  asm("v_pk_add_f32 %0, %1, %0" : "+v"(c) : "v"(a));
}
__device__ inline float asf(unsigned u) { union { unsigned u; float f; } c; c.u = u; return c.f; }
__device__ inline unsigned asu(float f) { union { float f; unsigned u; } c; c.f = f; return c.u; }
__device__ inline unsigned bf16rne(float f) {  // round-to-nearest-even bf16 bits
  unsigned u = asu(f);
  return (u + 0x7fffu + ((u >> 16) & 1u)) >> 16;
}

// Fold BPB partials of one column-quad q (0..127) for batch b, add bias,
// squash over D2 (4-lane shfl), write 4 floats to vout[q*4..]. Deterministic
// (same order every caller) -> redundant per-block copies are bit-identical.
__device__ inline void foldv(const float* __restrict__ P,
                             const float* __restrict__ bias, float scale,
                             int b, int q, float* vout) {
  v4f s = {0.f, 0.f, 0.f, 0.f};
  const float* base = P + (size_t)b * BPB * ROW_ + q * 4;
#pragma unroll 4
  for (int k = 0; k < BPB; ++k)
    s += *reinterpret_cast<const v4f*>(base + (size_t)k * ROW_);
  const v4f bq = *reinterpret_cast<const v4f*>(bias + q * 4);
  v4f t = s * scale + bq;
  float sq = t.x * t.x + t.y * t.y + t.z * t.z + t.w * t.w;
  sq += __shfl_xor(sq, 1, 4);
  sq += __shfl_xor(sq, 2, 4);
  const float f = sq / ((1.f + sq) * sqrtf(sq + 1e-8f));
  *reinterpret_cast<v4f*>(vout + q * 4) = t * f;
}

// PHASE 0: fp32 x (nontemporal), uniform weights, optional bf16 copy out.
// PHASE 1: weights = softmax(x.v0);  PHASE 2: weights = softmax(x.(v0+v1)).
// BF16 selects the xb input path for PHASE>=1.
template <int PHASE, bool BF16, bool WXB>
__global__ __launch_bounds__(TPB) void pass_k(
    const float* __restrict__ x, const unsigned short* __restrict__ xb,
    unsigned short* __restrict__ xbo, const float* __restrict__ bias,
    const float* __restrict__ P0, const float* __restrict__ P1,
    float* __restrict__ Pout) {
  const int tid = threadIdx.x;
  const int c2 = tid & 31, rs = tid >> 5;  // rs in 0..31
  const int b = blockIdx.x / BPB, blk = blockIdx.x % BPB;

  __shared__ alignas(16) float vbuf[2][ROW_];
  __shared__ alignas(16) float red[16][ROW_];

  v2f va[8];
  if (PHASE >= 1) {
    if (tid < 128) {
      foldv(P0, bias, 1.0f / C2_, b, tid, vbuf[0]);         // v0
    } else if (PHASE == 2 && tid < 256) {
      foldv(P1, bias, 1.0f, b, tid - 128, vbuf[1]);         // v1
    }
    __syncthreads();
    const float* v = &vbuf[0][c2 * D2_];
    const float* w = &vbuf[1][c2 * D2_];
#pragma unroll
    for (int j = 0; j < 8; ++j) {
      va[j].x = v[2 * j]     + (PHASE == 2 ? w[2 * j]     : 0.f);
      va[j].y = v[2 * j + 1] + (PHASE == 2 ? w[2 * j + 1] : 0.f);
    }
  }

  v4f acc4[4];
#pragma unroll
  for (int j = 0; j < 4; ++j) acc4[j] = (v4f){0.f, 0.f, 0.f, 0.f};
  v2f* acc = reinterpret_cast<v2f*>(acc4);

  const size_t off =
      ((size_t)b * C1_ + (size_t)blk * C1B) * ROW_ + (size_t)c2 * D2_;
#pragma unroll 2
  for (int r = rs; r < C1B; r += 32) {
    v2f xv[8];
    if (PHASE == 0 || !BF16) {
      const v4f* xp = reinterpret_cast<const v4f*>(x + off + (size_t)r * ROW_);
      v4f x4[4];
#pragma unroll
      for (int j = 0; j < 4; ++j)
        x4[j] = (PHASE == 0) ? __builtin_nontemporal_load(xp + j) : xp[j];
      const v2f* x2 = reinterpret_cast<const v2f*>(x4);
#pragma unroll
      for (int j = 0; j < 8; ++j) xv[j] = x2[j];
      if (PHASE == 0 && WXB) {  // bf16 copy (RNE), 2x16B stores
        const float* xf = reinterpret_cast<const float*>(x4);
        unsigned hw[8];
#pragma unroll
        for (int i = 0; i < 8; ++i)
          hw[i] = bf16rne(xf[2 * i]) | (bf16rne(xf[2 * i + 1]) << 16);
        v4u* hp = reinterpret_cast<v4u*>(xbo + off + (size_t)r * ROW_);
        hp[0] = (v4u){hw[0], hw[1], hw[2], hw[3]};
        hp[1] = (v4u){hw[4], hw[5], hw[6], hw[7]};
      }
    } else {
      const v4u* hp = reinterpret_cast<const v4u*>(xb + off + (size_t)r * ROW_);
      const v4u u0 = hp[0], u1 = hp[1];
      const unsigned u[8] = {u0.x, u0.y, u0.z, u0.w, u1.x, u1.y, u1.z, u1.w};
#pragma unroll
      for (int i = 0; i < 8; ++i) {
        xv[i].x = asf(u[i] << 16);
        xv[i].y = asf(u[i] & 0xffff0000u);
      }
    }

    if (PHASE == 0) {
#pragma unroll
      for (int j = 0; j < 8; ++j) pk_add(acc[j], xv[j]);
    } else {
      v2f dp = {0.f, 0.f};
#pragma unroll
      for (int j = 0; j < 8; ++j) pk_fma(dp, xv[j], va[j]);
      const float a = dp.x + dp.y;  // |a| <~ 15 -> exp safe without max-shift
      const float e = __expf(a);
      float s = e;
#pragma unroll
      for (int o = 16; o; o >>= 1) s += __shfl_xor(s, o, 32);
      const float w = e * __builtin_amdgcn_rcpf(s);
      const v2f w2 = {w, w};
#pragma unroll
      for (int j = 0; j < 8; ++j) pk_fma(acc[j], xv[j], w2);
    }
  }

  // tail: row-slot-pair reduce (lane l <-> l^32), 16 wave-partials via LDS,
  // block partial -> Pout[b][blk][512].
  float* af = reinterpret_cast<float*>(acc4);
#pragma unroll
  for (int k = 0; k < 16; ++k) af[k] += __shfl_xor(af[k], 32);
  const int wave = tid >> 6, lane = tid & 63;
  if (lane < 32) {
    v4f* dst = reinterpret_cast<v4f*>(&red[wave][c2 * D2_]);
    const v4f* s4 = reinterpret_cast<const v4f*>(acc4);
#pragma unroll
    for (int k = 0; k < 4; ++k) { const int jj = (k + c2) & 3; dst[jj] = s4[jj]; }
  }
  __syncthreads();
  if (tid < ROW_ / 4) {
    v4f s = {0.f, 0.f, 0.f, 0.f};
#pragma unroll 4
    for (int w = 0; w < 16; ++w) s += reinterpret_cast<const v4f*>(red[w])[tid];
    reinterpret_cast<v4f*>(Pout + ((size_t)b * BPB + blk) * ROW_)[tid] = s;
  }
}

// Final: fold P2 + bias, squash, write out. One thread per (b, column-quad).
__global__ __launch_bounds__(256) void squash_final(
    const float* __restrict__ P, const float* __restrict__ bias,
    float* __restrict__ out) {
  const int gid = blockIdx.x * 256 + threadIdx.x;  // 4096 = 32 b x 128 q
  const int q = gid & 127, b = gid >> 7;
  if (b >= B_) return;
  foldv(P, bias, 1.0f, b, q, out + (size_t)b * ROW_);
}

}  // namespace

extern "C" void kernel_launch(void* const* d_in, const int* in_sizes, int n_in,
                              void* d_out, int out_size, void* d_ws, size_t ws_size,
                              hipStream_t stream) {
  const float* x    = reinterpret_cast<const float*>(d_in[0]);  // digit_caps
  const float* bias = reinterpret_cast<const float*>(d_in[2]);
  float* out = reinterpret_cast<float*>(d_out);

  const size_t xb_elems = (size_t)B_ * C1_ * ROW_;   // 64 Mi bf16 = 128 MiB
  const size_t P_elems  = (size_t)B_ * BPB * ROW_;   // 1 MiB fp32 each
  const size_t need = xb_elems * 2 + 3 * P_elems * 4;

  const dim3 grid(B_ * BPB);   // 512 blocks
  const dim3 blk(TPB);         // 1024 threads
  const dim3 sgrid(16), sblk(256);

  if (ws_size >= need) {
    unsigned short* xb = reinterpret_cast<unsigned short*>(d_ws);
    float* P0 = reinterpret_cast<float*>(xb + xb_elems);
    float* P1 = P0 + P_elems;
    float* P2 = P1 + P_elems;
    pass_k<0, false, true><<<grid, blk, 0, stream>>>(x, nullptr, xb, bias,
                                                     nullptr, nullptr, P0);
    // PROBE: pass1 launched twice. Second launch reads the same P0/xb and
    // rewrites the identical P1 (deterministic). dur delta vs R5 == T(passN).
    pass_k<1, true, false><<<grid, blk, 0, stream>>>(x, xb, nullptr, bias,
                                                     P0, nullptr, P1);
    pass_k<1, true, false><<<grid, blk, 0, stream>>>(x, xb, nullptr, bias,
                                                     P0, nullptr, P1);
    pass_k<2, true, false><<<grid, blk, 0, stream>>>(x, xb, nullptr, bias,
                                                     P0, P1, P2);
    squash_final<<<sgrid, sblk, 0, stream>>>(P2, bias, out);
  } else {
    // fp32 fallback (no bf16 copy); needs only 3 MiB of workspace
    float* P0 = reinterpret_cast<float*>(d_ws);
    float* P1 = P0 + P_elems;
    float* P2 = P1 + P_elems;
    pass_k<0, false, false><<<grid, blk, 0, stream>>>(x, nullptr, nullptr, bias,
                                                      nullptr, nullptr, P0);
    pass_k<1, false, false><<<grid, blk, 0, stream>>>(x, nullptr, nullptr, bias,
                                                      P0, nullptr, P1);
    pass_k<2, false, false><<<grid, blk, 0, stream>>>(x, nullptr, nullptr, bias,
                                                      P0, P1, P2);
    squash_final<<<sgrid, sblk, 0, stream>>>(P2, bias, out);
  }
}

// Round 7
// 133.797 us; speedup vs baseline: 1.4815x; 1.4815x over previous
//
#include <hip/hip_runtime.h>
#include <cstddef>

// DynamicRouting: B=32, C1=4096, C2=32, D2=16, 3 routing iterations.
// digit_caps_stopped == digit_caps (bit-identical) -> read d_in[0] only.
//
// iter0: w = 1/32 uniform            -> v0 = squash(colsum(x)/32 + bias)
// iter1: w1 = softmax_c2(x.v0)       -> v1 = squash(sum_c1 w1*x + bias)
// iter2: w2 = softmax_c2(x.(v0+v1))  -> out = squash(sum_c1 w2*x + bias)
//
// R6 probe decomposition: pass0 ~102us (3.9 TB/s -- request-rate-bound from
// 64B-strided 16B lane reads), passN ~27us each. R7 rewrites pass0 with
// fully-contiguous per-wave 1KB loads: thread owns flat float4 (tid*4), and
// since the grid-stride (4096 floats = 8 rows) divides ROW=512, each thread's
// column offset is FIXED -> colsum accumulates in one v4f register.
// Fence-free (R3 lesson); cross-block sync = kernel boundaries only.

namespace {
typedef float  v2f __attribute__((ext_vector_type(2)));
typedef float  v4f __attribute__((ext_vector_type(4)));
typedef unsigned int v2u __attribute__((ext_vector_type(2)));
typedef unsigned int v4u __attribute__((ext_vector_type(4)));

constexpr int B_  = 32;
constexpr int C1_ = 4096;
constexpr int C2_ = 32;
constexpr int D2_ = 16;
constexpr int ROW_ = C2_ * D2_;   // 512 elems per (b,c1)
constexpr int BPB  = 16;          // partial blocks per batch element
constexpr int C1B  = C1_ / BPB;   // 256 rows per block
constexpr int TPB  = 1024;        // threads per block (16 waves)
constexpr int SEG_ = C1B * ROW_;  // 131072 floats per block segment

__device__ inline void pk_fma(v2f& c, v2f a, v2f b) {
  asm("v_pk_fma_f32 %0, %1, %2, %0" : "+v"(c) : "v"(a), "v"(b));
}
__device__ inline float asf(unsigned u) { union { unsigned u; float f; } c; c.u = u; return c.f; }
__device__ inline unsigned asu(float f) { union { float f; unsigned u; } c; c.f = f; return c.u; }
__device__ inline unsigned bf16rne(float f) {  // round-to-nearest-even bf16 bits
  unsigned u = asu(f);
  return (u + 0x7fffu + ((u >> 16) & 1u)) >> 16;
}

// Fold BPB partials of one column-quad q (0..127) for batch b, add bias,
// squash over D2 (4-lane shfl), write 4 floats to vout[q*4..]. Deterministic
// (same order every caller) -> redundant per-block copies are bit-identical.
__device__ inline void foldv(const float* __restrict__ P,
                             const float* __restrict__ bias, float scale,
                             int b, int q, float* vout) {
  v4f s = {0.f, 0.f, 0.f, 0.f};
  const float* base = P + (size_t)b * BPB * ROW_ + q * 4;
#pragma unroll 4
  for (int k = 0; k < BPB; ++k)
    s += *reinterpret_cast<const v4f*>(base + (size_t)k * ROW_);
  const v4f bq = *reinterpret_cast<const v4f*>(bias + q * 4);
  v4f t = s * scale + bq;
  float sq = t.x * t.x + t.y * t.y + t.z * t.z + t.w * t.w;
  sq += __shfl_xor(sq, 1, 4);
  sq += __shfl_xor(sq, 2, 4);
  const float f = sq / ((1.f + sq) * sqrtf(sq + 1e-8f));
  *reinterpret_cast<v4f*>(vout + q * 4) = t * f;
}

// Pass 0 (rewritten): fully-coalesced stream. Block owns a contiguous
// 512KB segment (256 rows). Thread tid reads float4 at tid*4 + it*4096;
// its column offset (tid*4)%512 is invariant -> register colsum. Also
// emits the bf16 copy (8B/lane contiguous stores).
__global__ __launch_bounds__(TPB) void pass0_coal(
    const float* __restrict__ x, unsigned short* __restrict__ xb,
    float* __restrict__ P) {
  const int tid = threadIdx.x;
  const size_t base = (size_t)blockIdx.x * SEG_;
  const float* xp = x + base + tid * 4;
  unsigned short* xo = xb + base + tid * 4;

  v4f acc = {0.f, 0.f, 0.f, 0.f};
#pragma unroll 4
  for (int it = 0; it < SEG_ / (TPB * 4); ++it) {
    const v4f v = __builtin_nontemporal_load(
        reinterpret_cast<const v4f*>(xp + (size_t)it * (TPB * 4)));
    acc += v;
    const v2u o = {bf16rne(v.x) | (bf16rne(v.y) << 16),
                   bf16rne(v.z) | (bf16rne(v.w) << 16)};
    *reinterpret_cast<v2u*>(xo + (size_t)it * (TPB * 4)) = o;
  }

  __shared__ alignas(16) float red[8][ROW_];  // 16 KiB
  const int s = tid >> 7, q = tid & 127;
  *reinterpret_cast<v4f*>(&red[s][q * 4]) = acc;
  __syncthreads();
  if (tid < 128) {
    v4f t = {0.f, 0.f, 0.f, 0.f};
#pragma unroll
    for (int k = 0; k < 8; ++k)
      t += *reinterpret_cast<const v4f*>(&red[k][tid * 4]);
    reinterpret_cast<v4f*>(P)[(size_t)blockIdx.x * 128 + tid] = t;
  }
}

// PHASE 0: fp32 x, uniform weights (fp32-fallback only).
// PHASE 1: weights = softmax(x.v0);  PHASE 2: weights = softmax(x.(v0+v1)).
// BF16 selects the xb input path for PHASE>=1.
template <int PHASE, bool BF16>
__global__ __launch_bounds__(TPB) void pass_k(
    const float* __restrict__ x, const unsigned short* __restrict__ xb,
    const float* __restrict__ bias, const float* __restrict__ P0,
    const float* __restrict__ P1, float* __restrict__ Pout) {
  const int tid = threadIdx.x;
  const int c2 = tid & 31, rs = tid >> 5;  // rs in 0..31
  const int b = blockIdx.x / BPB, blk = blockIdx.x % BPB;

  __shared__ alignas(16) float vbuf[2][ROW_];
  __shared__ alignas(16) float red[16][ROW_];

  v2f va[8];
  if (PHASE >= 1) {
    if (tid < 128) {
      foldv(P0, bias, 1.0f / C2_, b, tid, vbuf[0]);         // v0
    } else if (PHASE == 2 && tid < 256) {
      foldv(P1, bias, 1.0f, b, tid - 128, vbuf[1]);         // v1
    }
    __syncthreads();
    const float* v = &vbuf[0][c2 * D2_];
    const float* w = &vbuf[1][c2 * D2_];
#pragma unroll
    for (int j = 0; j < 8; ++j) {
      va[j].x = v[2 * j]     + (PHASE == 2 ? w[2 * j]     : 0.f);
      va[j].y = v[2 * j + 1] + (PHASE == 2 ? w[2 * j + 1] : 0.f);
    }
  }

  v4f acc4[4];
#pragma unroll
  for (int j = 0; j < 4; ++j) acc4[j] = (v4f){0.f, 0.f, 0.f, 0.f};
  v2f* acc = reinterpret_cast<v2f*>(acc4);

  const size_t off =
      ((size_t)b * C1_ + (size_t)blk * C1B) * ROW_ + (size_t)c2 * D2_;
#pragma unroll 2
  for (int r = rs; r < C1B; r += 32) {
    v2f xv[8];
    if (!BF16) {
      const v4f* xp = reinterpret_cast<const v4f*>(x + off + (size_t)r * ROW_);
      v4f x4[4];
#pragma unroll
      for (int j = 0; j < 4; ++j) x4[j] = xp[j];
      const v2f* x2 = reinterpret_cast<const v2f*>(x4);
#pragma unroll
      for (int j = 0; j < 8; ++j) xv[j] = x2[j];
    } else {
      const v4u* hp = reinterpret_cast<const v4u*>(xb + off + (size_t)r * ROW_);
      const v4u u0 = hp[0], u1 = hp[1];
      const unsigned u[8] = {u0.x, u0.y, u0.z, u0.w, u1.x, u1.y, u1.z, u1.w};
#pragma unroll
      for (int i = 0; i < 8; ++i) {
        xv[i].x = asf(u[i] << 16);
        xv[i].y = asf(u[i] & 0xffff0000u);
      }
    }

    if (PHASE == 0) {
#pragma unroll
      for (int j = 0; j < 8; ++j) { acc[j].x += xv[j].x; acc[j].y += xv[j].y; }
    } else {
      v2f dp = {0.f, 0.f};
#pragma unroll
      for (int j = 0; j < 8; ++j) pk_fma(dp, xv[j], va[j]);
      const float a = dp.x + dp.y;  // |a| <~ 15 -> exp safe without max-shift
      const float e = __expf(a);
      float s = e;
#pragma unroll
      for (int o = 16; o; o >>= 1) s += __shfl_xor(s, o, 32);
      const float w = e * __builtin_amdgcn_rcpf(s);
      const v2f w2 = {w, w};
#pragma unroll
      for (int j = 0; j < 8; ++j) pk_fma(acc[j], xv[j], w2);
    }
  }

  // tail: row-slot-pair reduce (lane l <-> l^32), 16 wave-partials via LDS,
  // block partial -> Pout[b][blk][512].
  float* af = reinterpret_cast<float*>(acc4);
#pragma unroll
  for (int k = 0; k < 16; ++k) af[k] += __shfl_xor(af[k], 32);
  const int wave = tid >> 6, lane = tid & 63;
  if (lane < 32) {
    v4f* dst = reinterpret_cast<v4f*>(&red[wave][c2 * D2_]);
    const v4f* s4 = reinterpret_cast<const v4f*>(acc4);
#pragma unroll
    for (int k = 0; k < 4; ++k) { const int jj = (k + c2) & 3; dst[jj] = s4[jj]; }
  }
  __syncthreads();
  if (tid < ROW_ / 4) {
    v4f s = {0.f, 0.f, 0.f, 0.f};
#pragma unroll 4
    for (int w = 0; w < 16; ++w) s += reinterpret_cast<const v4f*>(red[w])[tid];
    reinterpret_cast<v4f*>(Pout + ((size_t)b * BPB + blk) * ROW_)[tid] = s;
  }
}

// Final: fold P2 + bias, squash, write out. One thread per (b, column-quad).
__global__ __launch_bounds__(256) void squash_final(
    const float* __restrict__ P, const float* __restrict__ bias,
    float* __restrict__ out) {
  const int gid = blockIdx.x * 256 + threadIdx.x;  // 4096 = 32 b x 128 q
  const int q = gid & 127, b = gid >> 7;
  if (b >= B_) return;
  foldv(P, bias, 1.0f, b, q, out + (size_t)b * ROW_);
}

}  // namespace

extern "C" void kernel_launch(void* const* d_in, const int* in_sizes, int n_in,
                              void* d_out, int out_size, void* d_ws, size_t ws_size,
                              hipStream_t stream) {
  const float* x    = reinterpret_cast<const float*>(d_in[0]);  // digit_caps
  const float* bias = reinterpret_cast<const float*>(d_in[2]);
  float* out = reinterpret_cast<float*>(d_out);

  const size_t xb_elems = (size_t)B_ * C1_ * ROW_;   // 64 Mi bf16 = 128 MiB
  const size_t P_elems  = (size_t)B_ * BPB * ROW_;   // 1 MiB fp32 each
  const size_t need = xb_elems * 2 + 3 * P_elems * 4;

  const dim3 grid(B_ * BPB);   // 512 blocks
  const dim3 blk(TPB);         // 1024 threads
  const dim3 sgrid(16), sblk(256);

  if (ws_size >= need) {
    unsigned short* xb = reinterpret_cast<unsigned short*>(d_ws);
    float* P0 = reinterpret_cast<float*>(xb + xb_elems);
    float* P1 = P0 + P_elems;
    float* P2 = P1 + P_elems;
    pass0_coal<<<grid, blk, 0, stream>>>(x, xb, P0);
    pass_k<1, true><<<grid, blk, 0, stream>>>(x, xb, bias, P0, nullptr, P1);
    pass_k<2, true><<<grid, blk, 0, stream>>>(x, xb, bias, P0, P1, P2);
    squash_final<<<sgrid, sblk, 0, stream>>>(P2, bias, out);
  } else {
    // fp32 fallback (no bf16 copy); needs only 3 MiB of workspace
    float* P0 = reinterpret_cast<float*>(d_ws);
    float* P1 = P0 + P_elems;
    float* P2 = P1 + P_elems;
    pass_k<0, false><<<grid, blk, 0, stream>>>(x, nullptr, bias, nullptr, nullptr, P0);
    pass_k<1, false><<<grid, blk, 0, stream>>>(x, nullptr, bias, P0, nullptr, P1);
    pass_k<2, false><<<grid, blk, 0, stream>>>(x, nullptr, bias, P0, P1, P2);
    squash_final<<<sgrid, sblk, 0, stream>>>(P2, bias, out);
  }
}

// Round 8
// 126.019 us; speedup vs baseline: 1.5729x; 1.0617x over previous
//
#include <hip/hip_runtime.h>
#include <cstddef>

// DynamicRouting: B=32, C1=4096, C2=32, D2=16, 3 routing iterations.
// digit_caps_stopped == digit_caps (bit-identical) -> read d_in[0] only.
//
// iter0: w = 1/32 uniform            -> v0 = squash(colsum(x)/32 + bias)
// iter1: w1 = softmax_c2(x.v0)       -> v1 = squash(sum_c1 w1*x + bias)
// iter2: w2 = softmax_c2(x.(v0+v1))  -> out = squash(sum_c1 w2*x + bias)
//
// R7 lesson (pass0, 4x): line-touch rate, not DRAM bytes, limits strided
// streams. R8 applies the same fix to passN (2x): one contiguous 16B load
// per lane (8 elems), lane pair (tid^1) shares a (row,c2) chunk; pair-merge
// via shfl_xor(1); softmax butterfly {2,4,8,16,32} sums each c2 once.
// Fence-free (R3); cross-block sync = kernel boundaries only.

namespace {
typedef float  v2f __attribute__((ext_vector_type(2)));
typedef float  v4f __attribute__((ext_vector_type(4)));
typedef unsigned int v2u __attribute__((ext_vector_type(2)));
typedef unsigned int v4u __attribute__((ext_vector_type(4)));

constexpr int B_  = 32;
constexpr int C1_ = 4096;
constexpr int C2_ = 32;
constexpr int D2_ = 16;
constexpr int ROW_ = C2_ * D2_;   // 512 elems per (b,c1)
constexpr int BPB  = 16;          // partial blocks per batch element
constexpr int C1B  = C1_ / BPB;   // 256 rows per block
constexpr int TPB  = 1024;        // threads per block (16 waves)
constexpr int SEG_ = C1B * ROW_;  // 131072 elems per block segment

__device__ inline void pk_fma(v2f& c, v2f a, v2f b) {
  asm("v_pk_fma_f32 %0, %1, %2, %0" : "+v"(c) : "v"(a), "v"(b));
}
__device__ inline float asf(unsigned u) { union { unsigned u; float f; } c; c.u = u; return c.f; }
__device__ inline unsigned asu(float f) { union { float f; unsigned u; } c; c.f = f; return c.u; }
__device__ inline unsigned bf16rne(float f) {  // round-to-nearest-even bf16 bits
  unsigned u = asu(f);
  return (u + 0x7fffu + ((u >> 16) & 1u)) >> 16;
}

// Fold BPB partials of one column-quad q (0..127) for batch b, add bias,
// squash over D2 (4-lane shfl), write 4 floats to vout[q*4..]. Deterministic
// -> redundant per-block copies are bit-identical.
__device__ inline void foldv(const float* __restrict__ P,
                             const float* __restrict__ bias, float scale,
                             int b, int q, float* vout) {
  v4f s = {0.f, 0.f, 0.f, 0.f};
  const float* base = P + (size_t)b * BPB * ROW_ + q * 4;
#pragma unroll 4
  for (int k = 0; k < BPB; ++k)
    s += *reinterpret_cast<const v4f*>(base + (size_t)k * ROW_);
  const v4f bq = *reinterpret_cast<const v4f*>(bias + q * 4);
  v4f t = s * scale + bq;
  float sq = t.x * t.x + t.y * t.y + t.z * t.z + t.w * t.w;
  sq += __shfl_xor(sq, 1, 4);
  sq += __shfl_xor(sq, 2, 4);
  const float f = sq / ((1.f + sq) * sqrtf(sq + 1e-8f));
  *reinterpret_cast<v4f*>(vout + q * 4) = t * f;
}

// Pass 0: fully-coalesced stream (R7). Block owns a contiguous 512KB
// segment; thread tid reads float4 at tid*4 + it*4096; column offset
// invariant -> register colsum. Also emits the bf16 copy (8B/lane).
__global__ __launch_bounds__(TPB) void pass0_coal(
    const float* __restrict__ x, unsigned short* __restrict__ xb,
    float* __restrict__ P) {
  const int tid = threadIdx.x;
  const size_t base = (size_t)blockIdx.x * SEG_;
  const float* xp = x + base + tid * 4;
  unsigned short* xo = xb + base + tid * 4;

  v4f acc = {0.f, 0.f, 0.f, 0.f};
#pragma unroll 4
  for (int it = 0; it < SEG_ / (TPB * 4); ++it) {
    const v4f v = __builtin_nontemporal_load(
        reinterpret_cast<const v4f*>(xp + (size_t)it * (TPB * 4)));
    acc += v;
    const v2u o = {bf16rne(v.x) | (bf16rne(v.y) << 16),
                   bf16rne(v.z) | (bf16rne(v.w) << 16)};
    *reinterpret_cast<v2u*>(xo + (size_t)it * (TPB * 4)) = o;
  }

  __shared__ alignas(16) float red[8][ROW_];  // 16 KiB
  const int s = tid >> 7, q = tid & 127;
  *reinterpret_cast<v4f*>(&red[s][q * 4]) = acc;
  __syncthreads();
  if (tid < 128) {
    v4f t = {0.f, 0.f, 0.f, 0.f};
#pragma unroll
    for (int k = 0; k < 8; ++k)
      t += *reinterpret_cast<const v4f*>(&red[k][tid * 4]);
    reinterpret_cast<v4f*>(P)[(size_t)blockIdx.x * 128 + tid] = t;
  }
}

// Passes 1/2 (R8): contiguous 16B/lane loads. Per iter each WAVE handles one
// row (64 lanes = 32 c2 x 2 d-halves); block handles 16 rows/iter, 16 iters.
// PHASE 1: w = softmax(x.v0); PHASE 2: w = softmax(x.(v0+v1)).
template <int PHASE>
__global__ __launch_bounds__(TPB) void passN_c(
    const unsigned short* __restrict__ xb, const float* __restrict__ bias,
    const float* __restrict__ P0, const float* __restrict__ P1,
    float* __restrict__ Pout) {
  const int tid = threadIdx.x;
  const int b = blockIdx.x / BPB, blk = blockIdx.x % BPB;
  const int lane6 = tid & 63;          // (c2, dhalf) = (lane6>>1, lane6&1)
  const int voff = lane6 * 8;          // 8-float slice of the 512-row layout

  __shared__ alignas(16) float vbuf[2][ROW_];
  __shared__ alignas(16) float red[16][ROW_];

  if (tid < 128) {
    foldv(P0, bias, 1.0f / C2_, b, tid, vbuf[0]);           // v0
  } else if (PHASE == 2 && tid < 256) {
    foldv(P1, bias, 1.0f, b, tid - 128, vbuf[1]);           // v1
  }
  __syncthreads();

  v2f va[4];  // logit vector slice: v0 (phase1) or v0+v1 (phase2)
  {
    const v2f* vp = reinterpret_cast<const v2f*>(&vbuf[0][voff]);
#pragma unroll
    for (int j = 0; j < 4; ++j) va[j] = vp[j];
    if (PHASE == 2) {
      const v2f* wp = reinterpret_cast<const v2f*>(&vbuf[1][voff]);
#pragma unroll
      for (int j = 0; j < 4; ++j) va[j] += wp[j];
    }
  }

  v4f acc4[2] = {{0.f, 0.f, 0.f, 0.f}, {0.f, 0.f, 0.f, 0.f}};
  v2f* acc = reinterpret_cast<v2f*>(acc4);

  const unsigned short* seg = xb + (size_t)blockIdx.x * SEG_;
#pragma unroll 4
  for (int k = 0; k < 16; ++k) {
    // contiguous: wave w reads row k*16+w as 64 x 16B back-to-back
    const v4u u4 = *reinterpret_cast<const v4u*>(seg + (size_t)k * 8192 + tid * 8);
    const unsigned u[4] = {u4.x, u4.y, u4.z, u4.w};
    v2f xv[4];
#pragma unroll
    for (int i = 0; i < 4; ++i) {
      xv[i].x = asf(u[i] << 16);
      xv[i].y = asf(u[i] & 0xffff0000u);
    }
    v2f dp = {0.f, 0.f};
#pragma unroll
    for (int i = 0; i < 4; ++i) pk_fma(dp, xv[i], va[i]);
    float a = dp.x + dp.y;
    a += __shfl_xor(a, 1);        // pair-merge: full 16-elem dot, both lanes
    const float e = __expf(a);    // |a| <~ 15 -> safe without max-shift
    float s = e;
#pragma unroll
    for (int o = 2; o <= 32; o <<= 1) s += __shfl_xor(s, o);
    const float w = e * __builtin_amdgcn_rcpf(s);  // each parity class = 32 distinct c2
    const v2f w2 = {w, w};
#pragma unroll
    for (int i = 0; i < 4; ++i) pk_fma(acc[i], xv[i], w2);
  }

  // tail: each wave holds a 512-elem partial (its 16 rows); LDS fold.
  const int wave = tid >> 6;
  v4f* dst = reinterpret_cast<v4f*>(&red[wave][voff]);
  dst[0] = acc4[0];
  dst[1] = acc4[1];
  __syncthreads();
  if (tid < ROW_ / 4) {
    v4f s = {0.f, 0.f, 0.f, 0.f};
#pragma unroll 4
    for (int w = 0; w < 16; ++w) s += reinterpret_cast<const v4f*>(red[w])[tid];
    reinterpret_cast<v4f*>(Pout + ((size_t)b * BPB + blk) * ROW_)[tid] = s;
  }
}

// Final: fold P2 + bias, squash, write out. One thread per (b, column-quad).
__global__ __launch_bounds__(256) void squash_final(
    const float* __restrict__ P, const float* __restrict__ bias,
    float* __restrict__ out) {
  const int gid = blockIdx.x * 256 + threadIdx.x;  // 4096 = 32 b x 128 q
  const int q = gid & 127, b = gid >> 7;
  if (b >= B_) return;
  foldv(P, bias, 1.0f, b, q, out + (size_t)b * ROW_);
}

// ---------- fp32 fallback (workspace too small; R5 structure) ----------
template <int PHASE>
__global__ __launch_bounds__(TPB) void fb_pass(
    const float* __restrict__ x, const float* __restrict__ bias,
    const float* __restrict__ P0, const float* __restrict__ P1,
    float* __restrict__ Pout) {
  const int tid = threadIdx.x;
  const int c2 = tid & 31, rs = tid >> 5;
  const int b = blockIdx.x / BPB, blk = blockIdx.x % BPB;
  __shared__ alignas(16) float vbuf[2][ROW_];
  __shared__ alignas(16) float red[16][ROW_];
  v2f va[8];
  if (PHASE >= 1) {
    if (tid < 128) foldv(P0, bias, 1.0f / C2_, b, tid, vbuf[0]);
    else if (PHASE == 2 && tid < 256) foldv(P1, bias, 1.0f, b, tid - 128, vbuf[1]);
    __syncthreads();
    const float* v = &vbuf[0][c2 * D2_];
    const float* w = &vbuf[1][c2 * D2_];
#pragma unroll
    for (int j = 0; j < 8; ++j) {
      va[j].x = v[2 * j]     + (PHASE == 2 ? w[2 * j]     : 0.f);
      va[j].y = v[2 * j + 1] + (PHASE == 2 ? w[2 * j + 1] : 0.f);
    }
  }
  v4f acc4[4];
#pragma unroll
  for (int j = 0; j < 4; ++j) acc4[j] = (v4f){0.f, 0.f, 0.f, 0.f};
  v2f* acc = reinterpret_cast<v2f*>(acc4);
  const size_t off = ((size_t)b * C1_ + (size_t)blk * C1B) * ROW_ + (size_t)c2 * D2_;
  for (int r = rs; r < C1B; r += 32) {
    const v4f* xp = reinterpret_cast<const v4f*>(x + off + (size_t)r * ROW_);
    v4f x4[4];
#pragma unroll
    for (int j = 0; j < 4; ++j) x4[j] = xp[j];
    v2f* x2 = reinterpret_cast<v2f*>(x4);
    float w = 1.0f;
    if (PHASE >= 1) {
      v2f dp = {0.f, 0.f};
#pragma unroll
      for (int j = 0; j < 8; ++j) pk_fma(dp, x2[j], va[j]);
      const float a = dp.x + dp.y;
      const float e = __expf(a);
      float s = e;
#pragma unroll
      for (int o = 16; o; o >>= 1) s += __shfl_xor(s, o, 32);
      w = e * __builtin_amdgcn_rcpf(s);
    }
    const v2f w2 = {w, w};
#pragma unroll
    for (int j = 0; j < 8; ++j) pk_fma(acc[j], x2[j], w2);
  }
  float* af = reinterpret_cast<float*>(acc4);
#pragma unroll
  for (int k = 0; k < 16; ++k) af[k] += __shfl_xor(af[k], 32);
  const int wave = tid >> 6, lane = tid & 63;
  if (lane < 32) {
    v4f* dst = reinterpret_cast<v4f*>(&red[wave][c2 * D2_]);
    const v4f* s4 = reinterpret_cast<const v4f*>(acc4);
#pragma unroll
    for (int k = 0; k < 4; ++k) { const int jj = (k + c2) & 3; dst[jj] = s4[jj]; }
  }
  __syncthreads();
  if (tid < ROW_ / 4) {
    v4f s = {0.f, 0.f, 0.f, 0.f};
#pragma unroll 4
    for (int w = 0; w < 16; ++w) s += reinterpret_cast<const v4f*>(red[w])[tid];
    reinterpret_cast<v4f*>(Pout + ((size_t)b * BPB + blk) * ROW_)[tid] = s;
  }
}

}  // namespace

extern "C" void kernel_launch(void* const* d_in, const int* in_sizes, int n_in,
                              void* d_out, int out_size, void* d_ws, size_t ws_size,
                              hipStream_t stream) {
  const float* x    = reinterpret_cast<const float*>(d_in[0]);  // digit_caps
  const float* bias = reinterpret_cast<const float*>(d_in[2]);
  float* out = reinterpret_cast<float*>(d_out);

  const size_t xb_elems = (size_t)B_ * C1_ * ROW_;   // 64 Mi bf16 = 128 MiB
  const size_t P_elems  = (size_t)B_ * BPB * ROW_;   // 1 MiB fp32 each
  const size_t need = xb_elems * 2 + 3 * P_elems * 4;

  const dim3 grid(B_ * BPB);   // 512 blocks
  const dim3 blk(TPB);         // 1024 threads
  const dim3 sgrid(16), sblk(256);

  if (ws_size >= need) {
    unsigned short* xb = reinterpret_cast<unsigned short*>(d_ws);
    float* P0 = reinterpret_cast<float*>(xb + xb_elems);
    float* P1 = P0 + P_elems;
    float* P2 = P1 + P_elems;
    pass0_coal<<<grid, blk, 0, stream>>>(x, xb, P0);
    passN_c<1><<<grid, blk, 0, stream>>>(xb, bias, P0, nullptr, P1);
    passN_c<2><<<grid, blk, 0, stream>>>(xb, bias, P0, P1, P2);
    squash_final<<<sgrid, sblk, 0, stream>>>(P2, bias, out);
  } else {
    float* P0 = reinterpret_cast<float*>(d_ws);
    float* P1 = P0 + P_elems;
    float* P2 = P1 + P_elems;
    fb_pass<0><<<grid, blk, 0, stream>>>(x, bias, nullptr, nullptr, P0);
    fb_pass<1><<<grid, blk, 0, stream>>>(x, bias, P0, nullptr, P1);
    fb_pass<2><<<grid, blk, 0, stream>>>(x, bias, P0, P1, P2);
    squash_final<<<sgrid, sblk, 0, stream>>>(P2, bias, out);
  }
}

// Round 9
// 125.606 us; speedup vs baseline: 1.5781x; 1.0033x over previous
//
#include <hip/hip_runtime.h>
#include <cstddef>

// DynamicRouting: B=32, C1=4096, C2=32, D2=16, 3 routing iterations.
// digit_caps_stopped == digit_caps (bit-identical) -> read d_in[0] only.
//
// iter0: w = 1/32 uniform            -> v0 = squash(colsum(x)/32 + bias)
// iter1: w1 = softmax_c2(x.v0)       -> v1 = squash(sum_c1 w1*x + bias)
// iter2: w2 = softmax_c2(x.(v0+v1))  -> out = squash(sum_c1 w2*x + bias)
//
// Structure: 4 launches, fence-free (R3: agent-scope fences flush per-XCD
// L2s, 10x). R7/R8 lesson: line-touch rate limits strided streams -> all
// passes use fully-contiguous per-lane loads. R9: pass0 widens to 8
// floats/lane (2x16B NT loads) so the bf16 copy is a full 16B/lane store
// (1KB wave-stores, half the store-instruction rate).

namespace {
typedef float  v2f __attribute__((ext_vector_type(2)));
typedef float  v4f __attribute__((ext_vector_type(4)));
typedef unsigned int v4u __attribute__((ext_vector_type(4)));

constexpr int B_  = 32;
constexpr int C1_ = 4096;
constexpr int C2_ = 32;
constexpr int D2_ = 16;
constexpr int ROW_ = C2_ * D2_;   // 512 elems per (b,c1)
constexpr int BPB  = 16;          // partial blocks per batch element
constexpr int C1B  = C1_ / BPB;   // 256 rows per block
constexpr int TPB  = 1024;        // threads per block (16 waves)
constexpr int SEG_ = C1B * ROW_;  // 131072 elems per block segment

__device__ inline void pk_fma(v2f& c, v2f a, v2f b) {
  asm("v_pk_fma_f32 %0, %1, %2, %0" : "+v"(c) : "v"(a), "v"(b));
}
__device__ inline float asf(unsigned u) { union { unsigned u; float f; } c; c.u = u; return c.f; }
__device__ inline unsigned asu(float f) { union { float f; unsigned u; } c; c.f = f; return c.u; }
__device__ inline unsigned bf16rne(float f) {  // round-to-nearest-even bf16 bits
  unsigned u = asu(f);
  return (u + 0x7fffu + ((u >> 16) & 1u)) >> 16;
}

// Fold BPB partials of one column-quad q (0..127) for batch b, add bias,
// squash over D2 (4-lane shfl), write 4 floats to vout[q*4..]. Deterministic
// -> redundant per-block copies are bit-identical.
__device__ inline void foldv(const float* __restrict__ P,
                             const float* __restrict__ bias, float scale,
                             int b, int q, float* vout) {
  v4f s = {0.f, 0.f, 0.f, 0.f};
  const float* base = P + (size_t)b * BPB * ROW_ + q * 4;
#pragma unroll 4
  for (int k = 0; k < BPB; ++k)
    s += *reinterpret_cast<const v4f*>(base + (size_t)k * ROW_);
  const v4f bq = *reinterpret_cast<const v4f*>(bias + q * 4);
  v4f t = s * scale + bq;
  float sq = t.x * t.x + t.y * t.y + t.z * t.z + t.w * t.w;
  sq += __shfl_xor(sq, 1, 4);
  sq += __shfl_xor(sq, 2, 4);
  const float f = sq / ((1.f + sq) * sqrtf(sq + 1e-8f));
  *reinterpret_cast<v4f*>(vout + q * 4) = t * f;
}

// Pass 0 (R9): 8 floats/lane per iter (2x16B NT loads, 32B contiguous);
// bf16 copy becomes one full 16B store/lane (1KB wave-stores). Column
// offset (tid*8)%512 invariant (stride 8192 = 16 rows divides 512) ->
// colsum lives in two v4f registers.
__global__ __launch_bounds__(TPB) void pass0_coal(
    const float* __restrict__ x, unsigned short* __restrict__ xb,
    float* __restrict__ P) {
  const int tid = threadIdx.x;
  const size_t base = (size_t)blockIdx.x * SEG_;
  const float* xp = x + base + tid * 8;
  unsigned short* xo = xb + base + tid * 8;

  v4f acc0 = {0.f, 0.f, 0.f, 0.f}, acc1 = {0.f, 0.f, 0.f, 0.f};
#pragma unroll 4
  for (int it = 0; it < SEG_ / (TPB * 8); ++it) {  // 16 iters
    const size_t o = (size_t)it * (TPB * 8);
    const v4f a = __builtin_nontemporal_load(
        reinterpret_cast<const v4f*>(xp + o));
    const v4f b2 = __builtin_nontemporal_load(
        reinterpret_cast<const v4f*>(xp + o + 4));
    acc0 += a;
    acc1 += b2;
    const v4u w = {bf16rne(a.x)  | (bf16rne(a.y)  << 16),
                   bf16rne(a.z)  | (bf16rne(a.w)  << 16),
                   bf16rne(b2.x) | (bf16rne(b2.y) << 16),
                   bf16rne(b2.z) | (bf16rne(b2.w) << 16)};
    *reinterpret_cast<v4u*>(xo + o) = w;
  }

  __shared__ alignas(16) float red[16][ROW_];  // 32 KiB
  const int s = tid >> 6, o8 = (tid & 63) * 8;
  *reinterpret_cast<v4f*>(&red[s][o8]) = acc0;
  *reinterpret_cast<v4f*>(&red[s][o8 + 4]) = acc1;
  __syncthreads();
  if (tid < 128) {
    v4f t = {0.f, 0.f, 0.f, 0.f};
#pragma unroll
    for (int k = 0; k < 16; ++k)
      t += *reinterpret_cast<const v4f*>(&red[k][tid * 4]);
    reinterpret_cast<v4f*>(P)[(size_t)blockIdx.x * 128 + tid] = t;
  }
}

// Passes 1/2 (R8): contiguous 16B/lane loads; wave = one row (32 c2 x 2
// d-halves); pair-merge shfl_xor(1); softmax butterfly {2..32}.
// PHASE 2 reads xb nontemporally (last consumer).
template <int PHASE>
__global__ __launch_bounds__(TPB) void passN_c(
    const unsigned short* __restrict__ xb, const float* __restrict__ bias,
    const float* __restrict__ P0, const float* __restrict__ P1,
    float* __restrict__ Pout) {
  const int tid = threadIdx.x;
  const int b = blockIdx.x / BPB, blk = blockIdx.x % BPB;
  const int lane6 = tid & 63;          // (c2, dhalf) = (lane6>>1, lane6&1)
  const int voff = lane6 * 8;          // 8-float slice of the 512-row layout

  __shared__ alignas(16) float vbuf[2][ROW_];
  __shared__ alignas(16) float red[16][ROW_];

  if (tid < 128) {
    foldv(P0, bias, 1.0f / C2_, b, tid, vbuf[0]);           // v0
  } else if (PHASE == 2 && tid < 256) {
    foldv(P1, bias, 1.0f, b, tid - 128, vbuf[1]);           // v1
  }
  __syncthreads();

  v2f va[4];  // logit vector slice: v0 (phase1) or v0+v1 (phase2)
  {
    const v2f* vp = reinterpret_cast<const v2f*>(&vbuf[0][voff]);
#pragma unroll
    for (int j = 0; j < 4; ++j) va[j] = vp[j];
    if (PHASE == 2) {
      const v2f* wp = reinterpret_cast<const v2f*>(&vbuf[1][voff]);
#pragma unroll
      for (int j = 0; j < 4; ++j) va[j] += wp[j];
    }
  }

  v4f acc4[2] = {{0.f, 0.f, 0.f, 0.f}, {0.f, 0.f, 0.f, 0.f}};
  v2f* acc = reinterpret_cast<v2f*>(acc4);

  const unsigned short* seg = xb + (size_t)blockIdx.x * SEG_;
#pragma unroll 4
  for (int k = 0; k < 16; ++k) {
    const v4u* p = reinterpret_cast<const v4u*>(seg + (size_t)k * 8192 + tid * 8);
    const v4u u4 = (PHASE == 2) ? __builtin_nontemporal_load(p) : *p;
    const unsigned u[4] = {u4.x, u4.y, u4.z, u4.w};
    v2f xv[4];
#pragma unroll
    for (int i = 0; i < 4; ++i) {
      xv[i].x = asf(u[i] << 16);
      xv[i].y = asf(u[i] & 0xffff0000u);
    }
    v2f dp = {0.f, 0.f};
#pragma unroll
    for (int i = 0; i < 4; ++i) pk_fma(dp, xv[i], va[i]);
    float a = dp.x + dp.y;
    a += __shfl_xor(a, 1);        // pair-merge: full 16-elem dot, both lanes
    const float e = __expf(a);    // |a| <~ 15 -> safe without max-shift
    float s = e;
#pragma unroll
    for (int o = 2; o <= 32; o <<= 1) s += __shfl_xor(s, o);
    const float w = e * __builtin_amdgcn_rcpf(s);
    const v2f w2 = {w, w};
#pragma unroll
    for (int i = 0; i < 4; ++i) pk_fma(acc[i], xv[i], w2);
  }

  // tail: each wave holds a 512-elem partial (its 16 rows); LDS fold.
  const int wave = tid >> 6;
  v4f* dst = reinterpret_cast<v4f*>(&red[wave][voff]);
  dst[0] = acc4[0];
  dst[1] = acc4[1];
  __syncthreads();
  if (tid < ROW_ / 4) {
    v4f s = {0.f, 0.f, 0.f, 0.f};
#pragma unroll 4
    for (int w = 0; w < 16; ++w) s += reinterpret_cast<const v4f*>(red[w])[tid];
    reinterpret_cast<v4f*>(Pout + ((size_t)b * BPB + blk) * ROW_)[tid] = s;
  }
}

// Final: fold P2 + bias, squash, write out. One thread per (b, column-quad).
__global__ __launch_bounds__(256) void squash_final(
    const float* __restrict__ P, const float* __restrict__ bias,
    float* __restrict__ out) {
  const int gid = blockIdx.x * 256 + threadIdx.x;  // 4096 = 32 b x 128 q
  const int q = gid & 127, b = gid >> 7;
  if (b >= B_) return;
  foldv(P, bias, 1.0f, b, q, out + (size_t)b * ROW_);
}

// ---------- fp32 fallback (workspace too small; R5 structure) ----------
template <int PHASE>
__global__ __launch_bounds__(TPB) void fb_pass(
    const float* __restrict__ x, const float* __restrict__ bias,
    const float* __restrict__ P0, const float* __restrict__ P1,
    float* __restrict__ Pout) {
  const int tid = threadIdx.x;
  const int c2 = tid & 31, rs = tid >> 5;
  const int b = blockIdx.x / BPB, blk = blockIdx.x % BPB;
  __shared__ alignas(16) float vbuf[2][ROW_];
  __shared__ alignas(16) float red[16][ROW_];
  v2f va[8];
  if (PHASE >= 1) {
    if (tid < 128) foldv(P0, bias, 1.0f / C2_, b, tid, vbuf[0]);
    else if (PHASE == 2 && tid < 256) foldv(P1, bias, 1.0f, b, tid - 128, vbuf[1]);
    __syncthreads();
    const float* v = &vbuf[0][c2 * D2_];
    const float* w = &vbuf[1][c2 * D2_];
#pragma unroll
    for (int j = 0; j < 8; ++j) {
      va[j].x = v[2 * j]     + (PHASE == 2 ? w[2 * j]     : 0.f);
      va[j].y = v[2 * j + 1] + (PHASE == 2 ? w[2 * j + 1] : 0.f);
    }
  }
  v4f acc4[4];
#pragma unroll
  for (int j = 0; j < 4; ++j) acc4[j] = (v4f){0.f, 0.f, 0.f, 0.f};
  v2f* acc = reinterpret_cast<v2f*>(acc4);
  const size_t off = ((size_t)b * C1_ + (size_t)blk * C1B) * ROW_ + (size_t)c2 * D2_;
  for (int r = rs; r < C1B; r += 32) {
    const v4f* xp = reinterpret_cast<const v4f*>(x + off + (size_t)r * ROW_);
    v4f x4[4];
#pragma unroll
    for (int j = 0; j < 4; ++j) x4[j] = xp[j];
    v2f* x2 = reinterpret_cast<v2f*>(x4);
    float w = 1.0f;
    if (PHASE >= 1) {
      v2f dp = {0.f, 0.f};
#pragma unroll
      for (int j = 0; j < 8; ++j) pk_fma(dp, x2[j], va[j]);
      const float a = dp.x + dp.y;
      const float e = __expf(a);
      float s = e;
#pragma unroll
      for (int o = 16; o; o >>= 1) s += __shfl_xor(s, o, 32);
      w = e * __builtin_amdgcn_rcpf(s);
    }
    const v2f w2 = {w, w};
#pragma unroll
    for (int j = 0; j < 8; ++j) pk_fma(acc[j], x2[j], w2);
  }
  float* af = reinterpret_cast<float*>(acc4);
#pragma unroll
  for (int k = 0; k < 16; ++k) af[k] += __shfl_xor(af[k], 32);
  const int wave = tid >> 6, lane = tid & 63;
  if (lane < 32) {
    v4f* dst = reinterpret_cast<v4f*>(&red[wave][c2 * D2_]);
    const v4f* s4 = reinterpret_cast<const v4f*>(acc4);
#pragma unroll
    for (int k = 0; k < 4; ++k) { const int jj = (k + c2) & 3; dst[jj] = s4[jj]; }
  }
  __syncthreads();
  if (tid < ROW_ / 4) {
    v4f s = {0.f, 0.f, 0.f, 0.f};
#pragma unroll 4
    for (int w = 0; w < 16; ++w) s += reinterpret_cast<const v4f*>(red[w])[tid];
    reinterpret_cast<v4f*>(Pout + ((size_t)b * BPB + blk) * ROW_)[tid] = s;
  }
}

}  // namespace

extern "C" void kernel_launch(void* const* d_in, const int* in_sizes, int n_in,
                              void* d_out, int out_size, void* d_ws, size_t ws_size,
                              hipStream_t stream) {
  const float* x    = reinterpret_cast<const float*>(d_in[0]);  // digit_caps
  const float* bias = reinterpret_cast<const float*>(d_in[2]);
  float* out = reinterpret_cast<float*>(d_out);

  const size_t xb_elems = (size_t)B_ * C1_ * ROW_;   // 64 Mi bf16 = 128 MiB
  const size_t P_elems  = (size_t)B_ * BPB * ROW_;   // 1 MiB fp32 each
  const size_t need = xb_elems * 2 + 3 * P_elems * 4;

  const dim3 grid(B_ * BPB);   // 512 blocks
  const dim3 blk(TPB);         // 1024 threads
  const dim3 sgrid(16), sblk(256);

  if (ws_size >= need) {
    unsigned short* xb = reinterpret_cast<unsigned short*>(d_ws);
    float* P0 = reinterpret_cast<float*>(xb + xb_elems);
    float* P1 = P0 + P_elems;
    float* P2 = P1 + P_elems;
    pass0_coal<<<grid, blk, 0, stream>>>(x, xb, P0);
    passN_c<1><<<grid, blk, 0, stream>>>(xb, bias, P0, nullptr, P1);
    passN_c<2><<<grid, blk, 0, stream>>>(xb, bias, P0, P1, P2);
    squash_final<<<sgrid, sblk, 0, stream>>>(P2, bias, out);
  } else {
    float* P0 = reinterpret_cast<float*>(d_ws);
    float* P1 = P0 + P_elems;
    float* P2 = P1 + P_elems;
    fb_pass<0><<<grid, blk, 0, stream>>>(x, bias, nullptr, nullptr, P0);
    fb_pass<1><<<grid, blk, 0, stream>>>(x, bias, P0, nullptr, P1);
    fb_pass<2><<<grid, blk, 0, stream>>>(x, bias, P0, P1, P2);
    squash_final<<<sgrid, sblk, 0, stream>>>(P2, bias, out);
  }
}